// Round 2
// baseline (629.460 us; speedup 1.0000x reference)
//
#include <hip/hip_runtime.h>

#define R 256
#define C 32
#define NCELL1 32                       // cells per axis
#define NCELLS (NCELL1 * NCELL1 * NCELL1)
#define PER_WAVE 256                    // sorted points per wave chunk

// ---------------------------------------------------------------------------
// Convert + transpose: (3, C, R, R) f32 -> (3, R, R, C) bf16 (stored ushort).
__global__ __launch_bounds__(256) void convert_kernel(const float* __restrict__ tri,
                                                      ushort* __restrict__ tw) {
    int p = blockIdx.x >> 8;        // blockIdx.x = p*R + y
    int y = blockIdx.x & (R - 1);
    int x = threadIdx.x;

    unsigned packed[C / 2];         // 16 dwords = 32 bf16
#pragma unroll
    for (int i = 0; i < C / 2; ++i) {
        unsigned w = 0;
#pragma unroll
        for (int h = 0; h < 2; ++h) {
            float f = tri[(((p * C + (2 * i + h)) * R) + y) * R + x];
            unsigned u = __float_as_uint(f);
            unsigned r = (u + 0x7fffu + ((u >> 16) & 1u)) >> 16;  // RNE bf16
            w |= (r & 0xffffu) << (16 * h);
        }
        packed[i] = w;
    }
    uint4* dst = (uint4*)(tw + ((size_t)(p * R + y) * R + x) * C);
#pragma unroll
    for (int i = 0; i < 4; ++i) {
        dst[i] = make_uint4(packed[4 * i], packed[4 * i + 1],
                            packed[4 * i + 2], packed[4 * i + 3]);
    }
}

// ---------------------------------------------------------------------------
// Spatial binning (counting sort by 32^3 cell).
__device__ __forceinline__ int cell_of(float px, float py, float pz) {
    int cx = min(max((int)((px + 1.0f) * 16.0f), 0), NCELL1 - 1);
    int cy = min(max((int)((py + 1.0f) * 16.0f), 0), NCELL1 - 1);
    int cz = min(max((int)((pz + 1.0f) * 16.0f), 0), NCELL1 - 1);
    return (cz * NCELL1 + cy) * NCELL1 + cx;
}

__global__ __launch_bounds__(256) void zero_kernel(unsigned* __restrict__ h) {
    h[blockIdx.x * 256 + threadIdx.x] = 0u;
}

__global__ __launch_bounds__(256) void hist_kernel(const float* __restrict__ xyz,
                                                   unsigned* __restrict__ hist, int M) {
    int m = blockIdx.x * 256 + threadIdx.x;
    if (m >= M) return;
    float px = xyz[3 * m + 0], py = xyz[3 * m + 1], pz = xyz[3 * m + 2];
    atomicAdd(&hist[cell_of(px, py, pz)], 1u);
}

// Exclusive scan of NCELLS counts, single block of 1024 threads, 32 per thread.
__global__ __launch_bounds__(1024) void scan_kernel(unsigned* __restrict__ hist) {
    __shared__ unsigned part[1024];
    int t = threadIdx.x;
    unsigned local[32];
    unsigned total = 0;
#pragma unroll
    for (int i = 0; i < 32; ++i) {
        local[i] = total;                       // exclusive within-thread
        total += hist[t * 32 + i];
    }
    part[t] = total;
    __syncthreads();
    // inclusive Hillis-Steele over 1024 partials
    for (int d = 1; d < 1024; d <<= 1) {
        unsigned v = (t >= d) ? part[t - d] : 0u;
        __syncthreads();
        part[t] += v;
        __syncthreads();
    }
    unsigned base = part[t] - total;            // exclusive base for this thread
#pragma unroll
    for (int i = 0; i < 32; ++i) hist[t * 32 + i] = base + local[i];
}

// Scatter sorted records {px,py,pz, bits(m)}; offs becomes end-offsets (unused after).
__global__ __launch_bounds__(256) void scatter_kernel(const float* __restrict__ xyz,
                                                      unsigned* __restrict__ offs,
                                                      float4* __restrict__ srt, int M) {
    int m = blockIdx.x * 256 + threadIdx.x;
    if (m >= M) return;
    float px = xyz[3 * m + 0], py = xyz[3 * m + 1], pz = xyz[3 * m + 2];
    unsigned slot = atomicAdd(&offs[cell_of(px, py, pz)], 1u);
    srt[slot] = make_float4(px, py, pz, __int_as_float(m));
}

// ---------------------------------------------------------------------------
// One tap's 8 channels (4 dwords of packed bf16) into 8 accumulators.
__device__ __forceinline__ void tap_fma(uint4 v, float w, float* acc) {
    unsigned d[4] = {v.x, v.y, v.z, v.w};
#pragma unroll
    for (int k = 0; k < 4; ++k) {
        acc[2 * k]     = fmaf(w, __uint_as_float(d[k] << 16),          acc[2 * k]);
        acc[2 * k + 1] = fmaf(w, __uint_as_float(d[k] & 0xffff0000u), acc[2 * k + 1]);
    }
}

// Core sampling for one point given its coords; writes out[mo*C + 8*cq .. +8).
__device__ __forceinline__ void sample_point(float px, float py, float pz, int mo,
                                             const ushort* __restrict__ twc,
                                             float* __restrict__ out, int cq) {
    float uu[3] = {py, pz, py};
    float vv[3] = {px, px, pz};

    float acc[8];
#pragma unroll
    for (int j = 0; j < 8; ++j) acc[j] = 0.0f;

#pragma unroll
    for (int p = 0; p < 3; ++p) {
        float ix = (uu[p] + 1.0f) * 0.5f * 255.0f;
        float iy = (vv[p] + 1.0f) * 0.5f * 255.0f;
        int   x0 = (int)ix;                 // coords >= 0: trunc == floor
        int   y0 = (int)iy;
        float wx1 = ix - (float)x0;
        float wy1 = iy - (float)y0;
        float wx0 = 1.0f - wx1;
        float wy0 = 1.0f - wy1;
        int x1 = min(x0 + 1, R - 1);        // weight 0 when clamped
        int y1 = min(y0 + 1, R - 1);

        float w00 = wx0 * wy0, w01 = wx1 * wy0, w10 = wx0 * wy1, w11 = wx1 * wy1;

        const ushort* pl = twc + (size_t)p * R * R * C;
        uint4 v00 = *(const uint4*)(pl + (y0 * R + x0) * C);
        uint4 v01 = *(const uint4*)(pl + (y0 * R + x1) * C);
        uint4 v10 = *(const uint4*)(pl + (y1 * R + x0) * C);
        uint4 v11 = *(const uint4*)(pl + (y1 * R + x1) * C);

        tap_fma(v00, w00, acc);
        tap_fma(v01, w01, acc);
        tap_fma(v10, w10, acc);
        tap_fma(v11, w11, acc);
    }

    float4* o = (float4*)(out + (size_t)mo * C + 8 * cq);
    o[0] = make_float4(acc[0], acc[1], acc[2], acc[3]);
    o[1] = make_float4(acc[4], acc[5], acc[6], acc[7]);
}

// Sorted-order sampler: each WAVE owns a contiguous chunk of PER_WAVE sorted
// points; within the wave, the 16 quads process 16 CONSECUTIVE points per
// iteration (lane-interleaved), so each iteration's taps cover ~1 cell's
// ~15 KB plane footprint -> L1/L2 hits, and same-line tap requests coalesce.
__global__ __launch_bounds__(256) void sample_sorted(const float4* __restrict__ srt,
                                                     const ushort* __restrict__ tw,
                                                     float* __restrict__ out, int M) {
    int gtid = blockIdx.x * 256 + threadIdx.x;
    int wave = gtid >> 6;
    int lane = threadIdx.x & 63;
    int quad = lane >> 2;           // 0..15
    int cq   = lane & 3;            // channel octet
    const ushort* twc = tw + 8 * cq;

    int base = wave * PER_WAVE;
#pragma unroll 1
    for (int i = quad; i < PER_WAVE; i += 16) {
        int m = base + i;
        if (m < M) {
            float4 r = srt[m];      // 4 lanes share 16 B -> broadcast
            sample_point(r.x, r.y, r.z, __float_as_int(r.w), twc, out, cq);
        }
    }
}

// Fallback (unsorted) sampler, used only if workspace is too small.
__global__ __launch_bounds__(256) void sample_kernel(const float* __restrict__ xyz,
                                                     const ushort* __restrict__ tw,
                                                     float* __restrict__ out, int M) {
    int tid = blockIdx.x * 256 + threadIdx.x;
    int q   = tid >> 2;
    int cq  = tid & 3;
    int nq  = (gridDim.x * 256) >> 2;
    const ushort* twc = tw + 8 * cq;
    for (int m = q; m < M; m += nq) {
        float px = xyz[3 * m + 0], py = xyz[3 * m + 1], pz = xyz[3 * m + 2];
        sample_point(px, py, pz, m, twc, out, cq);
    }
}

// ---------------------------------------------------------------------------
extern "C" void kernel_launch(void* const* d_in, const int* in_sizes, int n_in,
                              void* d_out, int out_size, void* d_ws, size_t ws_size,
                              hipStream_t stream) {
    const float* xyz = (const float*)d_in[0];
    const float* tri = (const float*)d_in[1];  // (3, C, R, R) f32
    float* out = (float*)d_out;                // (M, C) f32

    int M = in_sizes[0] / 3;

    // Workspace layout: tw (12 MiB) | hist (128 KiB) | srt (M * 16 B)
    size_t tw_bytes   = (size_t)3 * R * R * C * sizeof(ushort);
    size_t hist_bytes = (size_t)NCELLS * sizeof(unsigned);
    size_t srt_off    = tw_bytes + hist_bytes;
    size_t need       = srt_off + (size_t)M * sizeof(float4);

    ushort*   tw   = (ushort*)d_ws;
    unsigned* hist = (unsigned*)((char*)d_ws + tw_bytes);
    float4*   srt  = (float4*)((char*)d_ws + srt_off);

    convert_kernel<<<3 * R, 256, 0, stream>>>(tri, tw);

    if (ws_size >= need) {
        int mb = (M + 255) / 256;
        zero_kernel<<<NCELLS / 256, 256, 0, stream>>>(hist);
        hist_kernel<<<mb, 256, 0, stream>>>(xyz, hist, M);
        scan_kernel<<<1, 1024, 0, stream>>>(hist);
        scatter_kernel<<<mb, 256, 0, stream>>>(xyz, hist, srt, M);

        int nwaves = (M + PER_WAVE - 1) / PER_WAVE;
        int blocks = (nwaves + 3) / 4;          // 4 waves per block
        sample_sorted<<<blocks, 256, 0, stream>>>(srt, tw, out, M);
    } else {
        sample_kernel<<<4096, 256, 0, stream>>>(xyz, tw, out, M);
    }
}

// Round 3
// 489.607 us; speedup vs baseline: 1.2856x; 1.2856x over previous
//
#include <hip/hip_runtime.h>

#define R 256
#define C 32
#define NCELL1 32                        // cells per axis
#define NCELLS (NCELL1 * NCELL1 * NCELL1)
#define CAP 128                          // bucket capacity per cell (avg load ~61)

// ---------------------------------------------------------------------------
// Convert + transpose: (3, C, R, R) f32 -> (3, R, R, C) bf16 (stored ushort).
// Side duty: first 128 blocks zero the 32K cell counters; block 128 zeros the
// overflow counter (saves a dedicated zero_kernel dispatch).
__global__ __launch_bounds__(256) void convert_kernel(const float* __restrict__ tri,
                                                      ushort* __restrict__ tw,
                                                      unsigned* __restrict__ cnt,
                                                      unsigned* __restrict__ ovcnt) {
    if (blockIdx.x < NCELLS / 256)
        cnt[blockIdx.x * 256 + threadIdx.x] = 0u;
    if (blockIdx.x == NCELLS / 256 && threadIdx.x == 0)
        *ovcnt = 0u;

    int p = blockIdx.x >> 8;        // blockIdx.x = p*R + y
    int y = blockIdx.x & (R - 1);
    int x = threadIdx.x;

    unsigned packed[C / 2];         // 16 dwords = 32 bf16
#pragma unroll
    for (int i = 0; i < C / 2; ++i) {
        unsigned w = 0;
#pragma unroll
        for (int h = 0; h < 2; ++h) {
            float f = tri[(((p * C + (2 * i + h)) * R) + y) * R + x];
            unsigned u = __float_as_uint(f);
            unsigned r = (u + 0x7fffu + ((u >> 16) & 1u)) >> 16;  // RNE bf16
            w |= (r & 0xffffu) << (16 * h);
        }
        packed[i] = w;
    }
    uint4* dst = (uint4*)(tw + ((size_t)(p * R + y) * R + x) * C);
#pragma unroll
    for (int i = 0; i < 4; ++i) {
        dst[i] = make_uint4(packed[4 * i], packed[4 * i + 1],
                            packed[4 * i + 2], packed[4 * i + 3]);
    }
}

// ---------------------------------------------------------------------------
__device__ __forceinline__ int cell_of(float px, float py, float pz) {
    int cx = min(max((int)((px + 1.0f) * 16.0f), 0), NCELL1 - 1);
    int cy = min(max((int)((py + 1.0f) * 16.0f), 0), NCELL1 - 1);
    int cz = min(max((int)((pz + 1.0f) * 16.0f), 0), NCELL1 - 1);
    return (cz * NCELL1 + cy) * NCELL1 + cx;
}

// One pass: bump-allocate a slot in the point's cell bucket; spill to the
// overflow list if the bucket is full (statistically never for uniform data,
// but correctness does not depend on that).
__global__ __launch_bounds__(256) void scatter_kernel(const float* __restrict__ xyz,
                                                      unsigned* __restrict__ cnt,
                                                      unsigned* __restrict__ ovcnt,
                                                      float4* __restrict__ buckets,
                                                      float4* __restrict__ ov, int M) {
    int m = blockIdx.x * 256 + threadIdx.x;
    if (m >= M) return;
    float px = xyz[3 * m + 0], py = xyz[3 * m + 1], pz = xyz[3 * m + 2];
    int cell = cell_of(px, py, pz);
    unsigned slot = atomicAdd(&cnt[cell], 1u);
    float4 rec = make_float4(px, py, pz, __int_as_float(m));
    if (slot < CAP) buckets[(size_t)cell * CAP + slot] = rec;
    else            ov[atomicAdd(ovcnt, 1u)] = rec;
}

// ---------------------------------------------------------------------------
// One tap's 8 channels (4 dwords of packed bf16) into 8 accumulators.
__device__ __forceinline__ void tap_fma(uint4 v, float w, float* acc) {
    unsigned d[4] = {v.x, v.y, v.z, v.w};
#pragma unroll
    for (int k = 0; k < 4; ++k) {
        acc[2 * k]     = fmaf(w, __uint_as_float(d[k] << 16),          acc[2 * k]);
        acc[2 * k + 1] = fmaf(w, __uint_as_float(d[k] & 0xffff0000u), acc[2 * k + 1]);
    }
}

// Core sampling for one point; writes out[mo*C + 8*cq .. +8).
__device__ __forceinline__ void sample_point(float px, float py, float pz, int mo,
                                             const ushort* __restrict__ twc,
                                             float* __restrict__ out, int cq) {
    float uu[3] = {py, pz, py};
    float vv[3] = {px, px, pz};

    float acc[8];
#pragma unroll
    for (int j = 0; j < 8; ++j) acc[j] = 0.0f;

#pragma unroll
    for (int p = 0; p < 3; ++p) {
        float ix = (uu[p] + 1.0f) * 0.5f * 255.0f;
        float iy = (vv[p] + 1.0f) * 0.5f * 255.0f;
        int   x0 = (int)ix;                 // coords >= 0: trunc == floor
        int   y0 = (int)iy;
        float wx1 = ix - (float)x0;
        float wy1 = iy - (float)y0;
        float wx0 = 1.0f - wx1;
        float wy0 = 1.0f - wy1;
        int x1 = min(x0 + 1, R - 1);        // weight 0 when clamped
        int y1 = min(y0 + 1, R - 1);

        float w00 = wx0 * wy0, w01 = wx1 * wy0, w10 = wx0 * wy1, w11 = wx1 * wy1;

        const ushort* pl = twc + (size_t)p * R * R * C;
        uint4 v00 = *(const uint4*)(pl + (y0 * R + x0) * C);
        uint4 v01 = *(const uint4*)(pl + (y0 * R + x1) * C);
        uint4 v10 = *(const uint4*)(pl + (y1 * R + x0) * C);
        uint4 v11 = *(const uint4*)(pl + (y1 * R + x1) * C);

        tap_fma(v00, w00, acc);
        tap_fma(v01, w01, acc);
        tap_fma(v10, w10, acc);
        tap_fma(v11, w11, acc);
    }

    float4* o = (float4*)(out + (size_t)mo * C + 8 * cq);
    o[0] = make_float4(acc[0], acc[1], acc[2], acc[3]);
    o[1] = make_float4(acc[4], acc[5], acc[6], acc[7]);
}

// Cell-walking sampler: each wave owns 4 contiguous cells; per iteration the
// wave's 16 quads consume 16 consecutive bucket entries of ONE cell, so the
// cell's ~15 KB plane footprint stays L1-resident while it's being used.
// XCD-chunked block swizzle keeps neighboring cells on the same L2.
__global__ __launch_bounds__(256) void sample_cells(const float4* __restrict__ buckets,
                                                    const unsigned* __restrict__ cnt,
                                                    const unsigned* __restrict__ ovcnt,
                                                    const float4* __restrict__ ov,
                                                    const ushort* __restrict__ tw,
                                                    float* __restrict__ out) {
    int nb  = gridDim.x;                         // multiple of 8
    int bid = blockIdx.x;
    int swz = (bid & 7) * (nb >> 3) + (bid >> 3);    // bijective XCD chunking

    int wave = swz * 4 + (threadIdx.x >> 6);
    int lane = threadIdx.x & 63;
    int quad = lane >> 2;            // 0..15
    int cq   = lane & 3;             // channel octet
    const ushort* twc = tw + 8 * cq;

    int nwaves = nb * 4;
    int cpw    = NCELLS / nwaves;    // cells per wave (4 at nb=2048)
    int c0     = wave * cpw;

    for (int c = c0; c < c0 + cpw; ++c) {
        int n = min((int)cnt[c], CAP);
        const float4* bk = buckets + (size_t)c * CAP;
        for (int i = quad; i < n; i += 16) {
            float4 r = bk[i];        // 4 lanes share 16 B -> broadcast
            sample_point(r.x, r.y, r.z, __float_as_int(r.w), twc, out, cq);
        }
    }

    // Overflow points (normally zero): generic grid-stride path.
    int nov = (int)*ovcnt;
    if (nov > 0) {
        int gq = (swz * 256 + (int)threadIdx.x) >> 2;
        int nq = (nb * 256) >> 2;
        for (int j = gq; j < nov; j += nq) {
            float4 r = ov[j];
            sample_point(r.x, r.y, r.z, __float_as_int(r.w), twc, out, cq);
        }
    }
}

// Fallback (unsorted) sampler, used only if workspace is too small.
__global__ __launch_bounds__(256) void sample_kernel(const float* __restrict__ xyz,
                                                     const ushort* __restrict__ tw,
                                                     float* __restrict__ out, int M) {
    int tid = blockIdx.x * 256 + threadIdx.x;
    int q   = tid >> 2;
    int cq  = tid & 3;
    int nq  = (gridDim.x * 256) >> 2;
    const ushort* twc = tw + 8 * cq;
    for (int m = q; m < M; m += nq) {
        float px = xyz[3 * m + 0], py = xyz[3 * m + 1], pz = xyz[3 * m + 2];
        sample_point(px, py, pz, m, twc, out, cq);
    }
}

// ---------------------------------------------------------------------------
extern "C" void kernel_launch(void* const* d_in, const int* in_sizes, int n_in,
                              void* d_out, int out_size, void* d_ws, size_t ws_size,
                              hipStream_t stream) {
    const float* xyz = (const float*)d_in[0];
    const float* tri = (const float*)d_in[1];  // (3, C, R, R) f32
    float* out = (float*)d_out;                // (M, C) f32

    int M = in_sizes[0] / 3;

    // Workspace: tw (12 MiB) | cnt (128 KiB) | ovcnt (128 B) | buckets (64 MiB)
    //            | ov (M * 16 B)
    size_t tw_bytes  = (size_t)3 * R * R * C * sizeof(ushort);
    size_t cnt_off   = tw_bytes;
    size_t ovc_off   = cnt_off + (size_t)NCELLS * sizeof(unsigned);
    size_t bkt_off   = ovc_off + 128;
    size_t ov_off    = bkt_off + (size_t)NCELLS * CAP * sizeof(float4);
    size_t need      = ov_off + (size_t)M * sizeof(float4);

    ushort*   tw      = (ushort*)d_ws;
    unsigned* cnt     = (unsigned*)((char*)d_ws + cnt_off);
    unsigned* ovcnt   = (unsigned*)((char*)d_ws + ovc_off);
    float4*   buckets = (float4*)((char*)d_ws + bkt_off);
    float4*   ov      = (float4*)((char*)d_ws + ov_off);

    if (ws_size >= need) {
        convert_kernel<<<3 * R, 256, 0, stream>>>(tri, tw, cnt, ovcnt);
        int mb = (M + 255) / 256;
        scatter_kernel<<<mb, 256, 0, stream>>>(xyz, cnt, ovcnt, buckets, ov, M);
        sample_cells<<<2048, 256, 0, stream>>>(buckets, cnt, ovcnt, ov, tw, out);
    } else {
        convert_kernel<<<3 * R, 256, 0, stream>>>(tri, tw, cnt, ovcnt);
        sample_kernel<<<4096, 256, 0, stream>>>(xyz, tw, out, M);
    }
}